// Round 1
// baseline (818.150 us; speedup 1.0000x reference)
//
#include <hip/hip_runtime.h>
#include <math.h>

#define NN 1024
#define BB 2
#define D 64
#define NHEAD 4
#define PH 16

__device__ __forceinline__ float wave_reduce_sum(float v) {
    #pragma unroll
    for (int off = 1; off < 64; off <<= 1)
        v += __shfl_xor(v, off, 64);
    return v;
}

// --- Kernel 1: normalized embedding rows ---------------------------------
__global__ __launch_bounds__(64) void k_normalize(const float* __restrict__ emb,
                                                  float* __restrict__ ne) {
    int i = blockIdx.x;
    int p = threadIdx.x;              // 0..63
    float v = emb[i * D + p];
    float ss = wave_reduce_sum(v * v);
    float nrm = fmaxf(sqrtf(ss), 1e-12f);
    ne[i * D + p] = v / nrm;
}

// --- Kernel 2: adjacency mask  mask[i,j] = (ne_i . ne_j != 0) | (i==j) ---
__global__ __launch_bounds__(256) void k_mask(const float* __restrict__ ne,
                                              unsigned char* __restrict__ mask) {
    int wave = threadIdx.x >> 6;
    int lane = threadIdx.x & 63;
    int i = blockIdx.x * 4 + wave;
    float nei = ne[i * D + lane];
    for (int j = 0; j < NN; ++j) {
        float v = nei * ne[j * D + lane];
        float s = wave_reduce_sum(v);
        if (lane == 0)
            mask[i * NN + j] = (s != 0.0f || j == i) ? 1 : 0;
    }
}

// --- Kernel 3: dual GEMM  xl = A@Wl, xr = A@Wr   (A: [M,64], W: [64,64]) -
__global__ __launch_bounds__(256) void k_gemm2(const float* __restrict__ A,
                                               const float* __restrict__ Wl,
                                               const float* __restrict__ Wr,
                                               float* __restrict__ xl,
                                               float* __restrict__ xr) {
    __shared__ float wl[64 * 64];
    __shared__ float wr[64 * 64];
    int tid = threadIdx.x;
    for (int t = tid; t < 4096; t += 256) { wl[t] = Wl[t]; wr[t] = Wr[t]; }
    __syncthreads();
    int r = blockIdx.x * 4 + (tid >> 6);
    int c = tid & 63;
    const float* arow = A + r * 64;
    float accl = 0.f, accr = 0.f;
    #pragma unroll
    for (int p = 0; p < 64; ++p) {
        float a = arow[p];
        accl = fmaf(a, wl[p * 64 + c], accl);
        accr = fmaf(a, wr[p * 64 + c], accr);
    }
    xl[r * 64 + c] = accl;
    xr[r * 64 + c] = accr;
}

// --- Kernel 4: fused GATv2 attention, one block per (b, i) ---------------
// e[h][j] = sum_p att[h,p]*lrelu(xr[i,h,p]+xl[j,h,p]); masked softmax over j;
// out[h,p] = (1/s_h) * sum_j pe[h][j]*xl[j,h,p] + bias; optional relu.
#define ESTRIDE 1089
template <bool RELU>
__global__ __launch_bounds__(256) void k_attn(const float* __restrict__ xl,
                                              const float* __restrict__ xr,
                                              const float* __restrict__ att,
                                              const float* __restrict__ bias,
                                              const unsigned char* __restrict__ mask,
                                              float* __restrict__ out) {
    __shared__ float e_lds[NHEAD * ESTRIDE];
    __shared__ float sinv[NHEAD];
    __shared__ float partial[4 * 64];

    int tid = threadIdx.x;
    int wave = tid >> 6;
    int lane = tid & 63;              // lane = h*16 + p
    int b = blockIdx.x >> 10;
    int i = blockIdx.x & (NN - 1);

    int h = lane >> 4;
    float attv = att[lane];                      // att[h][p] flat == lane
    float xri = xr[((b << 10) + i) * 64 + lane];
    const unsigned char* mrow = mask + i * NN;
    const float* xlb = xl + (b << 10) * 64;

    // Phase 1: raw scores
    for (int k = 0; k < 256; ++k) {
        int j = (wave << 8) + k;
        float v = xri + xlb[j * 64 + lane];
        v = v > 0.f ? v : 0.2f * v;              // leaky_relu slope 0.2
        float t = v * attv;
        t += __shfl_xor(t, 1, 64);
        t += __shfl_xor(t, 2, 64);
        t += __shfl_xor(t, 4, 64);
        t += __shfl_xor(t, 8, 64);               // 16-lane head-group sum
        float ev = mrow[j] ? t : -INFINITY;
        if ((lane & 15) == 0) e_lds[h * ESTRIDE + j] = ev;
    }
    __syncthreads();

    // Phase 2: softmax over j, one wave per head
    {
        int hh = wave;
        float m = -INFINITY;
        #pragma unroll
        for (int k = 0; k < 16; ++k)
            m = fmaxf(m, e_lds[hh * ESTRIDE + lane + (k << 6)]);
        #pragma unroll
        for (int off = 1; off < 64; off <<= 1)
            m = fmaxf(m, __shfl_xor(m, off, 64));
        float s = 0.f;
        #pragma unroll
        for (int k = 0; k < 16; ++k) {
            int idx = hh * ESTRIDE + lane + (k << 6);
            float pe = __expf(e_lds[idx] - m);   // exp(-inf)=0 for masked
            e_lds[idx] = pe;
            s += pe;
        }
        s = wave_reduce_sum(s);
        if (lane == 0) sinv[hh] = 1.0f / s;
    }
    __syncthreads();

    // Phase 3: weighted sum of xl over j
    float acc = 0.f;
    for (int k = 0; k < 256; ++k) {
        int j = (wave << 8) + k;
        acc = fmaf(e_lds[h * ESTRIDE + j], xlb[j * 64 + lane], acc);
    }
    partial[wave * 64 + lane] = acc;
    __syncthreads();
    if (tid < 64) {
        float s = partial[tid] + partial[64 + tid] + partial[128 + tid] + partial[192 + tid];
        float o = s * sinv[tid >> 4] + bias[tid];
        if (RELU) o = fmaxf(o, 0.f);
        out[((b << 10) + i) * 64 + tid] = o;
    }
}

extern "C" void kernel_launch(void* const* d_in, const int* in_sizes, int n_in,
                              void* d_out, int out_size, void* d_ws, size_t ws_size,
                              hipStream_t stream) {
    const float* x    = (const float*)d_in[0];   // [2,1024,64]
    const float* emb  = (const float*)d_in[1];   // [1024,64]
    const float* Wl1  = (const float*)d_in[2];
    const float* Wr1  = (const float*)d_in[3];
    const float* att1 = (const float*)d_in[4];
    const float* b1   = (const float*)d_in[5];
    const float* Wl2  = (const float*)d_in[6];
    const float* Wr2  = (const float*)d_in[7];
    const float* att2 = (const float*)d_in[8];
    const float* b2   = (const float*)d_in[9];
    float* out = (float*)d_out;

    // Workspace layout (bytes): ne 256K | mask 1M | xl 512K | xr 512K | h 512K
    float* ne = (float*)d_ws;
    unsigned char* mask = (unsigned char*)(ne + NN * D);
    float* xl = (float*)(mask + NN * NN);
    float* xr = xl + BB * NN * D;
    float* hbuf = xr + BB * NN * D;

    k_normalize<<<NN, 64, 0, stream>>>(emb, ne);
    k_mask<<<NN / 4, 256, 0, stream>>>(ne, mask);

    // Layer 1
    k_gemm2<<<BB * NN / 4, 256, 0, stream>>>(x, Wl1, Wr1, xl, xr);
    k_attn<true><<<BB * NN, 256, 0, stream>>>(xl, xr, att1, b1, mask, hbuf);

    // Layer 2
    k_gemm2<<<BB * NN / 4, 256, 0, stream>>>(hbuf, Wl2, Wr2, xl, xr);
    k_attn<false><<<BB * NN, 256, 0, stream>>>(xl, xr, att2, b2, mask, out);
}

// Round 2
// 218.827 us; speedup vs baseline: 3.7388x; 3.7388x over previous
//
#include <hip/hip_runtime.h>
#include <math.h>

#define NN 1024
#define BB 2
#define D 64
#define NHEAD 4
#define PH 16

__device__ __forceinline__ float wave_reduce_sum(float v) {
    #pragma unroll
    for (int off = 1; off < 64; off <<= 1)
        v += __shfl_xor(v, off, 64);
    return v;
}

// DPP move within 16-lane rows, bound_ctrl=1 (invalid lanes -> 0). VALU pipe only.
template <int CTRL>
__device__ __forceinline__ float dpp_mov(float x) {
    int xi = __builtin_bit_cast(int, x);
    int r = __builtin_amdgcn_update_dpp(0, xi, CTRL, 0xF, 0xF, true);
    return __builtin_bit_cast(float, r);
}

// 16-lane row sum via DPP row_shr 1,2,4,8; result valid in lane 15 of each row.
__device__ __forceinline__ float dpp_rowsum16(float t) {
    t += dpp_mov<0x111>(t);  // row_shr:1
    t += dpp_mov<0x112>(t);  // row_shr:2
    t += dpp_mov<0x114>(t);  // row_shr:4
    t += dpp_mov<0x118>(t);  // row_shr:8
    return t;
}

// --- Kernel 1: normalized embedding rows ---------------------------------
__global__ __launch_bounds__(64) void k_normalize(const float* __restrict__ emb,
                                                  float* __restrict__ ne) {
    int i = blockIdx.x;
    int p = threadIdx.x;
    float v = emb[i * D + p];
    float ss = wave_reduce_sum(v * v);
    float nrm = fmaxf(sqrtf(ss), 1e-12f);
    ne[i * D + p] = v / nrm;
}

// --- Kernel 2: adjacency mask as tiled GEMM ------------------------------
// mask[i,j] = (ne_i . ne_j != 0) | (i==j). 64x64 tile per block, 4x4/thread.
#define MST 65
__global__ __launch_bounds__(256) void k_mask(const float* __restrict__ ne,
                                              unsigned char* __restrict__ mask) {
    __shared__ float As[64 * MST];
    __shared__ float Bs[64 * MST];
    int tid = threadIdx.x;
    int ib = (blockIdx.x & 15) << 6;
    int jb = (blockIdx.x >> 4) << 6;

    #pragma unroll
    for (int r = 0; r < 4; ++r) {
        int q = tid + (r << 8);          // float4 index 0..1023
        int row = q >> 4, c4 = (q & 15) << 2;
        float4 a = *(const float4*)&ne[(ib + row) * D + c4];
        float4 b = *(const float4*)&ne[(jb + row) * D + c4];
        As[row * MST + c4 + 0] = a.x; As[row * MST + c4 + 1] = a.y;
        As[row * MST + c4 + 2] = a.z; As[row * MST + c4 + 3] = a.w;
        Bs[row * MST + c4 + 0] = b.x; Bs[row * MST + c4 + 1] = b.y;
        Bs[row * MST + c4 + 2] = b.z; Bs[row * MST + c4 + 3] = b.w;
    }
    __syncthreads();

    int i0 = (tid >> 4) << 2;   // 0..60
    int j0 = (tid & 15) << 2;   // 0..60
    float acc[4][4] = {};
    #pragma unroll 8
    for (int k = 0; k < 64; ++k) {
        float a0 = As[(i0 + 0) * MST + k];
        float a1 = As[(i0 + 1) * MST + k];
        float a2 = As[(i0 + 2) * MST + k];
        float a3 = As[(i0 + 3) * MST + k];
        float b0 = Bs[(j0 + 0) * MST + k];
        float b1 = Bs[(j0 + 1) * MST + k];
        float b2 = Bs[(j0 + 2) * MST + k];
        float b3 = Bs[(j0 + 3) * MST + k];
        acc[0][0] = fmaf(a0, b0, acc[0][0]); acc[0][1] = fmaf(a0, b1, acc[0][1]);
        acc[0][2] = fmaf(a0, b2, acc[0][2]); acc[0][3] = fmaf(a0, b3, acc[0][3]);
        acc[1][0] = fmaf(a1, b0, acc[1][0]); acc[1][1] = fmaf(a1, b1, acc[1][1]);
        acc[1][2] = fmaf(a1, b2, acc[1][2]); acc[1][3] = fmaf(a1, b3, acc[1][3]);
        acc[2][0] = fmaf(a2, b0, acc[2][0]); acc[2][1] = fmaf(a2, b1, acc[2][1]);
        acc[2][2] = fmaf(a2, b2, acc[2][2]); acc[2][3] = fmaf(a2, b3, acc[2][3]);
        acc[3][0] = fmaf(a3, b0, acc[3][0]); acc[3][1] = fmaf(a3, b1, acc[3][1]);
        acc[3][2] = fmaf(a3, b2, acc[3][2]); acc[3][3] = fmaf(a3, b3, acc[3][3]);
    }
    #pragma unroll
    for (int r = 0; r < 4; ++r) {
        int gi = ib + i0 + r;
        uchar4 m;
        m.x = (acc[r][0] != 0.f || gi == jb + j0 + 0) ? 1 : 0;
        m.y = (acc[r][1] != 0.f || gi == jb + j0 + 1) ? 1 : 0;
        m.z = (acc[r][2] != 0.f || gi == jb + j0 + 2) ? 1 : 0;
        m.w = (acc[r][3] != 0.f || gi == jb + j0 + 3) ? 1 : 0;
        *(uchar4*)&mask[gi * NN + jb + j0] = m;
    }
}

// --- Kernel 3: dual GEMM  xl = A@Wl, xr = A@Wr ---------------------------
__global__ __launch_bounds__(256) void k_gemm2(const float* __restrict__ A,
                                               const float* __restrict__ Wl,
                                               const float* __restrict__ Wr,
                                               float* __restrict__ xl,
                                               float* __restrict__ xr) {
    __shared__ float wl[64 * 64];
    __shared__ float wr[64 * 64];
    int tid = threadIdx.x;
    for (int t = tid; t < 4096; t += 256) { wl[t] = Wl[t]; wr[t] = Wr[t]; }
    __syncthreads();
    int r = blockIdx.x * 4 + (tid >> 6);
    int c = tid & 63;
    const float* arow = A + r * 64;
    float accl = 0.f, accr = 0.f;
    #pragma unroll
    for (int p = 0; p < 64; ++p) {
        float a = arow[p];
        accl = fmaf(a, wl[p * 64 + c], accl);
        accr = fmaf(a, wr[p * 64 + c], accr);
    }
    xl[r * 64 + c] = accl;
    xr[r * 64 + c] = accr;
}

// --- Kernel 4: fused GATv2 attention, one block per (b, i) ---------------
#define ES 1028
template <bool RELU>
__global__ __launch_bounds__(256) void k_attn(const float* __restrict__ xl,
                                              const float* __restrict__ xr,
                                              const float* __restrict__ att,
                                              const float* __restrict__ bias,
                                              const unsigned char* __restrict__ mask,
                                              float* __restrict__ out) {
    __shared__ float e_lds[NHEAD * ES];
    __shared__ float sinv[NHEAD];
    __shared__ float partial[4 * 64];

    int tid = threadIdx.x;
    int wave = tid >> 6;
    int lane = tid & 63;              // lane = h*16 + p
    int b = blockIdx.x >> 10;
    int i = blockIdx.x & (NN - 1);

    int h = lane >> 4;
    float attv = att[lane];
    float xri = xr[((b << 10) + i) * D + lane];
    const unsigned char* mrow = mask + i * NN;
    const float* xlb = xl + (b << 10) * D;
    int jbase = wave << 8;

    // Phase 1: raw scores; DPP row-reduce (VALU pipe), batched b128 e-writes.
    for (int k0 = 0; k0 < 256; k0 += 4) {
        unsigned mu = *(const unsigned*)(mrow + jbase + k0);
        float e4[4];
        #pragma unroll
        for (int u = 0; u < 4; ++u) {
            int j = jbase + k0 + u;
            float v = xri + xlb[j * D + lane];
            v = fmaxf(v, 0.f) + 0.2f * fminf(v, 0.f);   // leaky_relu 0.2
            float t = dpp_rowsum16(v * attv);           // valid in lane 15 of row
            e4[u] = ((mu >> (8 * u)) & 0xFF) ? t : -INFINITY;
        }
        if ((lane & 15) == 15) {
            *(float4*)&e_lds[h * ES + jbase + k0] =
                make_float4(e4[0], e4[1], e4[2], e4[3]);
        }
    }
    __syncthreads();

    // Phase 2: softmax over j, one wave per head
    {
        int hh = wave;
        float m = -INFINITY;
        #pragma unroll
        for (int k = 0; k < 16; ++k)
            m = fmaxf(m, e_lds[hh * ES + lane + (k << 6)]);
        #pragma unroll
        for (int off = 1; off < 64; off <<= 1)
            m = fmaxf(m, __shfl_xor(m, off, 64));
        float s = 0.f;
        #pragma unroll
        for (int k = 0; k < 16; ++k) {
            int idx = hh * ES + lane + (k << 6);
            float pe = __expf(e_lds[idx] - m);
            e_lds[idx] = pe;
            s += pe;
        }
        s = wave_reduce_sum(s);
        if (lane == 0) sinv[hh] = 1.0f / s;
    }
    __syncthreads();

    // Phase 3: weighted sum of xl over j; alpha via broadcast b128 reads.
    float acc = 0.f;
    const float* xw = xlb + jbase * D;
    for (int k0 = 0; k0 < 256; k0 += 4) {
        float4 p4 = *(const float4*)&e_lds[h * ES + jbase + k0];
        acc = fmaf(p4.x, xw[(k0 + 0) * D + lane], acc);
        acc = fmaf(p4.y, xw[(k0 + 1) * D + lane], acc);
        acc = fmaf(p4.z, xw[(k0 + 2) * D + lane], acc);
        acc = fmaf(p4.w, xw[(k0 + 3) * D + lane], acc);
    }
    partial[wave * 64 + lane] = acc;
    __syncthreads();
    if (tid < 64) {
        float s = partial[tid] + partial[64 + tid] + partial[128 + tid] + partial[192 + tid];
        float o = s * sinv[tid >> 4] + bias[tid];
        if (RELU) o = fmaxf(o, 0.f);
        out[((b << 10) + i) * D + tid] = o;
    }
}

extern "C" void kernel_launch(void* const* d_in, const int* in_sizes, int n_in,
                              void* d_out, int out_size, void* d_ws, size_t ws_size,
                              hipStream_t stream) {
    const float* x    = (const float*)d_in[0];
    const float* emb  = (const float*)d_in[1];
    const float* Wl1  = (const float*)d_in[2];
    const float* Wr1  = (const float*)d_in[3];
    const float* att1 = (const float*)d_in[4];
    const float* b1   = (const float*)d_in[5];
    const float* Wl2  = (const float*)d_in[6];
    const float* Wr2  = (const float*)d_in[7];
    const float* att2 = (const float*)d_in[8];
    const float* b2   = (const float*)d_in[9];
    float* out = (float*)d_out;

    float* ne = (float*)d_ws;
    unsigned char* mask = (unsigned char*)(ne + NN * D);
    float* xl = (float*)(mask + NN * NN);
    float* xr = xl + BB * NN * D;
    float* hbuf = xr + BB * NN * D;

    k_normalize<<<NN, 64, 0, stream>>>(emb, ne);
    k_mask<<<256, 256, 0, stream>>>(ne, mask);

    k_gemm2<<<BB * NN / 4, 256, 0, stream>>>(x, Wl1, Wr1, xl, xr);
    k_attn<true><<<BB * NN, 256, 0, stream>>>(xl, xr, att1, b1, mask, hbuf);

    k_gemm2<<<BB * NN / 4, 256, 0, stream>>>(hbuf, Wl2, Wr2, xl, xr);
    k_attn<false><<<BB * NN, 256, 0, stream>>>(xl, xr, att2, b2, mask, out);
}

// Round 3
// 181.806 us; speedup vs baseline: 4.5001x; 1.2036x over previous
//
#include <hip/hip_runtime.h>
#include <math.h>

#define NN 1024
#define BB 2
#define D 64
#define NHEAD 4
#define PH 16
#define ES 1040   // e_lds row stride (words); 1040%32==16 -> worst 2-way (free)

__device__ __forceinline__ float wave_reduce_sum(float v) {
    #pragma unroll
    for (int off = 1; off < 64; off <<= 1)
        v += __shfl_xor(v, off, 64);
    return v;
}

template <int CTRL>
__device__ __forceinline__ float dpp_mov(float x) {
    int xi = __builtin_bit_cast(int, x);
    int r = __builtin_amdgcn_update_dpp(0, xi, CTRL, 0xF, 0xF, true);
    return __builtin_bit_cast(float, r);
}

// 16-lane row sum; valid in lane 15 of each row.
__device__ __forceinline__ float dpp_rowsum16(float t) {
    t += dpp_mov<0x111>(t);
    t += dpp_mov<0x112>(t);
    t += dpp_mov<0x114>(t);
    t += dpp_mov<0x118>(t);
    return t;
}

// --- Kernel 1: normalized embedding rows ---------------------------------
__global__ __launch_bounds__(64) void k_normalize(const float* __restrict__ emb,
                                                  float* __restrict__ ne) {
    int i = blockIdx.x;
    int p = threadIdx.x;
    float v = emb[i * D + p];
    float ss = wave_reduce_sum(v * v);
    float nrm = fmaxf(sqrtf(ss), 1e-12f);
    ne[i * D + p] = v / nrm;
}

// --- Kernel 2: adjacency mask as tiled GEMM ------------------------------
#define MST 65
__global__ __launch_bounds__(256) void k_mask(const float* __restrict__ ne,
                                              unsigned char* __restrict__ mask) {
    __shared__ float As[64 * MST];
    __shared__ float Bs[64 * MST];
    int tid = threadIdx.x;
    int ib = (blockIdx.x & 15) << 6;
    int jb = (blockIdx.x >> 4) << 6;

    #pragma unroll
    for (int r = 0; r < 4; ++r) {
        int q = tid + (r << 8);
        int row = q >> 4, c4 = (q & 15) << 2;
        float4 a = *(const float4*)&ne[(ib + row) * D + c4];
        float4 b = *(const float4*)&ne[(jb + row) * D + c4];
        As[row * MST + c4 + 0] = a.x; As[row * MST + c4 + 1] = a.y;
        As[row * MST + c4 + 2] = a.z; As[row * MST + c4 + 3] = a.w;
        Bs[row * MST + c4 + 0] = b.x; Bs[row * MST + c4 + 1] = b.y;
        Bs[row * MST + c4 + 2] = b.z; Bs[row * MST + c4 + 3] = b.w;
    }
    __syncthreads();

    int i0 = (tid >> 4) << 2;
    int j0 = (tid & 15) << 2;
    float acc[4][4] = {};
    #pragma unroll 8
    for (int k = 0; k < 64; ++k) {
        float a0 = As[(i0 + 0) * MST + k];
        float a1 = As[(i0 + 1) * MST + k];
        float a2 = As[(i0 + 2) * MST + k];
        float a3 = As[(i0 + 3) * MST + k];
        float b0 = Bs[(j0 + 0) * MST + k];
        float b1 = Bs[(j0 + 1) * MST + k];
        float b2 = Bs[(j0 + 2) * MST + k];
        float b3 = Bs[(j0 + 3) * MST + k];
        acc[0][0] = fmaf(a0, b0, acc[0][0]); acc[0][1] = fmaf(a0, b1, acc[0][1]);
        acc[0][2] = fmaf(a0, b2, acc[0][2]); acc[0][3] = fmaf(a0, b3, acc[0][3]);
        acc[1][0] = fmaf(a1, b0, acc[1][0]); acc[1][1] = fmaf(a1, b1, acc[1][1]);
        acc[1][2] = fmaf(a1, b2, acc[1][2]); acc[1][3] = fmaf(a1, b3, acc[1][3]);
        acc[2][0] = fmaf(a2, b0, acc[2][0]); acc[2][1] = fmaf(a2, b1, acc[2][1]);
        acc[2][2] = fmaf(a2, b2, acc[2][2]); acc[2][3] = fmaf(a2, b3, acc[2][3]);
        acc[3][0] = fmaf(a3, b0, acc[3][0]); acc[3][1] = fmaf(a3, b1, acc[3][1]);
        acc[3][2] = fmaf(a3, b2, acc[3][2]); acc[3][3] = fmaf(a3, b3, acc[3][3]);
    }
    #pragma unroll
    for (int r = 0; r < 4; ++r) {
        int gi = ib + i0 + r;
        uchar4 m;
        m.x = (acc[r][0] != 0.f || gi == jb + j0 + 0) ? 1 : 0;
        m.y = (acc[r][1] != 0.f || gi == jb + j0 + 1) ? 1 : 0;
        m.z = (acc[r][2] != 0.f || gi == jb + j0 + 2) ? 1 : 0;
        m.w = (acc[r][3] != 0.f || gi == jb + j0 + 3) ? 1 : 0;
        *(uchar4*)&mask[gi * NN + jb + j0] = m;
    }
}

// --- Kernel 3: dual GEMM + al06 tail -------------------------------------
// xl = A@Wl, xr = A@Wr; al06[r][h] = 0.6 * sum_p att[h,p]*xl[r,h,p]
__global__ __launch_bounds__(256) void k_gemm2(const float* __restrict__ A,
                                               const float* __restrict__ Wl,
                                               const float* __restrict__ Wr,
                                               const float* __restrict__ att,
                                               float* __restrict__ xl,
                                               float* __restrict__ xr,
                                               float* __restrict__ al06) {
    __shared__ float wl[64 * 64];
    __shared__ float wr[64 * 64];
    int tid = threadIdx.x;
    for (int t = tid; t < 4096; t += 256) { wl[t] = Wl[t]; wr[t] = Wr[t]; }
    __syncthreads();
    int r = blockIdx.x * 4 + (tid >> 6);
    int c = tid & 63;
    float av = att[c];
    const float* arow = A + r * 64;
    float accl = 0.f, accr = 0.f;
    #pragma unroll
    for (int p = 0; p < 64; ++p) {
        float a = arow[p];
        accl = fmaf(a, wl[p * 64 + c], accl);
        accr = fmaf(a, wr[p * 64 + c], accr);
    }
    xl[r * 64 + c] = accl;
    xr[r * 64 + c] = accr;
    float t = dpp_rowsum16(accl * av);
    if ((c & 15) == 15) al06[(r << 2) | (c >> 4)] = 0.6f * t;
}

// --- Kernel 4: fused GATv2 attention, one block per (b, i-pair) ----------
// leaky_relu(v,0.2) = 0.6v + 0.4|v|  =>
// e[i,j,h] = ar06[i,h] + al06[j,h] + 0.4 * sum_p att[h,p]*|xr+xl|
template <bool RELU>
__global__ __launch_bounds__(256) void k_attn(const float* __restrict__ xl,
                                              const float* __restrict__ xr,
                                              const float* __restrict__ att,
                                              const float* __restrict__ al06,
                                              const float* __restrict__ bias,
                                              const unsigned char* __restrict__ mask,
                                              float* __restrict__ out) {
    __shared__ float eL[2][NHEAD][ES];
    __shared__ float partial[2][4][64];
    __shared__ float sinv[2][NHEAD];

    int tid = threadIdx.x;
    int wave = tid >> 6;
    int lane = tid & 63;
    int h = lane >> 4;
    int jl = lane & 15;
    int b = blockIdx.x >> 9;
    int i0 = (blockIdx.x & 511) << 1;
    int jbase = wave << 8;

    const float* xlb = xl + (b << 16);           // b*1024*64
    const float* alp = al06 + (b << 12);         // b*1024*4
    const unsigned char* mrow0 = mask + i0 * NN;
    const unsigned char* mrow1 = mrow0 + NN;

    // persistent per-lane fragments
    float at[16], xr0[16], xr1[16];
    {
        const float4* ap = (const float4*)(att + (h << 4));
        const float4* r0 = (const float4*)(xr + (((b << 10) + i0) << 6) + (h << 4));
        const float4* r1 = (const float4*)((const float*)r0 + 64);
        #pragma unroll
        for (int q = 0; q < 4; ++q) {
            *(float4*)&at[q << 2] = ap[q];
            *(float4*)&xr0[q << 2] = r0[q];
            *(float4*)&xr1[q << 2] = r1[q];
        }
    }
    float ar0 = 0.f, ar1 = 0.f;
    #pragma unroll
    for (int p = 0; p < 16; ++p) {
        ar0 = fmaf(at[p], xr0[p], ar0);
        ar1 = fmaf(at[p], xr1[p], ar1);
    }
    ar0 *= 0.6f; ar1 *= 0.6f;

    // Phase 1: scores. lane=(h,jl), serial p-reduction, no cross-lane ops.
    for (int s = 0; s < 16; ++s) {
        int j = jbase + (s << 4) + jl;
        const float4* xp = (const float4*)(xlb + (j << 6) + (h << 4));
        float xv[16];
        *(float4*)&xv[0]  = xp[0];
        *(float4*)&xv[4]  = xp[1];
        *(float4*)&xv[8]  = xp[2];
        *(float4*)&xv[12] = xp[3];
        float al = alp[(j << 2) | h];
        unsigned char m0 = mrow0[j], m1 = mrow1[j];
        float acc0 = 0.f, acc1 = 0.f;
        #pragma unroll
        for (int p = 0; p < 16; ++p) {
            float v0 = xr0[p] + xv[p];
            float v1 = xr1[p] + xv[p];
            acc0 = fmaf(at[p], __builtin_fabsf(v0), acc0);
            acc1 = fmaf(at[p], __builtin_fabsf(v1), acc1);
        }
        float e0 = fmaf(0.4f, acc0, ar0 + al);
        float e1 = fmaf(0.4f, acc1, ar1 + al);
        eL[0][h][j] = m0 ? e0 : -INFINITY;
        eL[1][h][j] = m1 ? e1 : -INFINITY;
    }
    __syncthreads();

    // Phase 2: softmax over j; wave w handles rows (ii=0,h=w) and (ii=1,h=w)
    #pragma unroll
    for (int ii = 0; ii < 2; ++ii) {
        float m = -INFINITY;
        #pragma unroll
        for (int k = 0; k < 16; ++k)
            m = fmaxf(m, eL[ii][wave][lane + (k << 6)]);
        #pragma unroll
        for (int off = 1; off < 64; off <<= 1)
            m = fmaxf(m, __shfl_xor(m, off, 64));
        float s = 0.f;
        #pragma unroll
        for (int k = 0; k < 16; ++k) {
            int idx = lane + (k << 6);
            float pe = __expf(eL[ii][wave][idx] - m);
            eL[ii][wave][idx] = pe;
            s += pe;
        }
        s = wave_reduce_sum(s);
        if (lane == 0) sinv[ii][wave] = 1.0f / s;
    }
    __syncthreads();

    // Phase 3: out[i,h,p] = sum_j alpha * xl[j,h,p]; lane=(h,p)
    float acc0 = 0.f, acc1 = 0.f;
    for (int k0 = 0; k0 < 256; k0 += 4) {
        int j = jbase + k0;
        float4 a0 = *(const float4*)&eL[0][h][j];
        float4 a1 = *(const float4*)&eL[1][h][j];
        float x0 = xlb[((j + 0) << 6) | lane];
        float x1 = xlb[((j + 1) << 6) | lane];
        float x2 = xlb[((j + 2) << 6) | lane];
        float x3 = xlb[((j + 3) << 6) | lane];
        acc0 = fmaf(a0.x, x0, acc0); acc1 = fmaf(a1.x, x0, acc1);
        acc0 = fmaf(a0.y, x1, acc0); acc1 = fmaf(a1.y, x1, acc1);
        acc0 = fmaf(a0.z, x2, acc0); acc1 = fmaf(a1.z, x2, acc1);
        acc0 = fmaf(a0.w, x3, acc0); acc1 = fmaf(a1.w, x3, acc1);
    }
    partial[0][wave][lane] = acc0;
    partial[1][wave][lane] = acc1;
    __syncthreads();
    if (tid < 128) {
        int ii = tid >> 6, c = tid & 63;
        float s = partial[ii][0][c] + partial[ii][1][c] +
                  partial[ii][2][c] + partial[ii][3][c];
        float o = s * sinv[ii][c >> 4] + bias[c];
        if (RELU) o = fmaxf(o, 0.f);
        out[((b << 10) + i0 + ii) * D + c] = o;
    }
}

extern "C" void kernel_launch(void* const* d_in, const int* in_sizes, int n_in,
                              void* d_out, int out_size, void* d_ws, size_t ws_size,
                              hipStream_t stream) {
    const float* x    = (const float*)d_in[0];
    const float* emb  = (const float*)d_in[1];
    const float* Wl1  = (const float*)d_in[2];
    const float* Wr1  = (const float*)d_in[3];
    const float* att1 = (const float*)d_in[4];
    const float* b1   = (const float*)d_in[5];
    const float* Wl2  = (const float*)d_in[6];
    const float* Wr2  = (const float*)d_in[7];
    const float* att2 = (const float*)d_in[8];
    const float* b2   = (const float*)d_in[9];
    float* out = (float*)d_out;

    float* ne = (float*)d_ws;                                   // 256KB
    unsigned char* mask = (unsigned char*)(ne + NN * D);        // 1MB
    float* xl = (float*)(mask + NN * NN);                       // 512KB
    float* xr = xl + BB * NN * D;                               // 512KB
    float* hbuf = xr + BB * NN * D;                             // 512KB
    float* al06 = hbuf + BB * NN * D;                           // 32KB

    k_normalize<<<NN, 64, 0, stream>>>(emb, ne);
    k_mask<<<256, 256, 0, stream>>>(ne, mask);

    k_gemm2<<<BB * NN / 4, 256, 0, stream>>>(x, Wl1, Wr1, att1, xl, xr, al06);
    k_attn<true><<<BB * NN / 2, 256, 0, stream>>>(xl, xr, att1, al06, b1, mask, hbuf);

    k_gemm2<<<BB * NN / 4, 256, 0, stream>>>(hbuf, Wl2, Wr2, att2, xl, xr, al06);
    k_attn<false><<<BB * NN / 2, 256, 0, stream>>>(xl, xr, att2, al06, b2, mask, out);
}

// Round 4
// 167.464 us; speedup vs baseline: 4.8855x; 1.0856x over previous
//
#include <hip/hip_runtime.h>
#include <math.h>

#define NN 1024
#define BB 2
#define D 64
#define NHEAD 4
#define PH 16
#define LOG2E 1.4426950408889634f

__device__ __forceinline__ float wave_reduce_sum(float v) {
    #pragma unroll
    for (int off = 1; off < 64; off <<= 1)
        v += __shfl_xor(v, off, 64);
    return v;
}

template <int CTRL>
__device__ __forceinline__ float dpp_mov(float x) {
    int xi = __builtin_bit_cast(int, x);
    int r = __builtin_amdgcn_update_dpp(0, xi, CTRL, 0xF, 0xF, true);
    return __builtin_bit_cast(float, r);
}

// 16-lane row sum; valid in lane 15 of each row of 16.
__device__ __forceinline__ float dpp_rowsum16(float t) {
    t += dpp_mov<0x111>(t);
    t += dpp_mov<0x112>(t);
    t += dpp_mov<0x114>(t);
    t += dpp_mov<0x118>(t);
    return t;
}

// --- Kernel 1: normalized embedding rows ---------------------------------
__global__ __launch_bounds__(64) void k_normalize(const float* __restrict__ emb,
                                                  float* __restrict__ ne) {
    int i = blockIdx.x;
    int p = threadIdx.x;
    float v = emb[i * D + p];
    float ss = wave_reduce_sum(v * v);
    float nrm = fmaxf(sqrtf(ss), 1e-12f);
    ne[i * D + p] = v / nrm;
}

// --- Kernel 2: adjacency mask as tiled GEMM ------------------------------
#define MST 65
__global__ __launch_bounds__(256) void k_mask(const float* __restrict__ ne,
                                              unsigned char* __restrict__ mask) {
    __shared__ float As[64 * MST];
    __shared__ float Bs[64 * MST];
    int tid = threadIdx.x;
    int ib = (blockIdx.x & 15) << 6;
    int jb = (blockIdx.x >> 4) << 6;

    #pragma unroll
    for (int r = 0; r < 4; ++r) {
        int q = tid + (r << 8);
        int row = q >> 4, c4 = (q & 15) << 2;
        float4 a = *(const float4*)&ne[(ib + row) * D + c4];
        float4 b = *(const float4*)&ne[(jb + row) * D + c4];
        As[row * MST + c4 + 0] = a.x; As[row * MST + c4 + 1] = a.y;
        As[row * MST + c4 + 2] = a.z; As[row * MST + c4 + 3] = a.w;
        Bs[row * MST + c4 + 0] = b.x; Bs[row * MST + c4 + 1] = b.y;
        Bs[row * MST + c4 + 2] = b.z; Bs[row * MST + c4 + 3] = b.w;
    }
    __syncthreads();

    int i0 = (tid >> 4) << 2;
    int j0 = (tid & 15) << 2;
    float acc[4][4] = {};
    #pragma unroll 8
    for (int k = 0; k < 64; ++k) {
        float a0 = As[(i0 + 0) * MST + k];
        float a1 = As[(i0 + 1) * MST + k];
        float a2 = As[(i0 + 2) * MST + k];
        float a3 = As[(i0 + 3) * MST + k];
        float b0 = Bs[(j0 + 0) * MST + k];
        float b1 = Bs[(j0 + 1) * MST + k];
        float b2 = Bs[(j0 + 2) * MST + k];
        float b3 = Bs[(j0 + 3) * MST + k];
        acc[0][0] = fmaf(a0, b0, acc[0][0]); acc[0][1] = fmaf(a0, b1, acc[0][1]);
        acc[0][2] = fmaf(a0, b2, acc[0][2]); acc[0][3] = fmaf(a0, b3, acc[0][3]);
        acc[1][0] = fmaf(a1, b0, acc[1][0]); acc[1][1] = fmaf(a1, b1, acc[1][1]);
        acc[1][2] = fmaf(a1, b2, acc[1][2]); acc[1][3] = fmaf(a1, b3, acc[1][3]);
        acc[2][0] = fmaf(a2, b0, acc[2][0]); acc[2][1] = fmaf(a2, b1, acc[2][1]);
        acc[2][2] = fmaf(a2, b2, acc[2][2]); acc[2][3] = fmaf(a2, b3, acc[2][3]);
        acc[3][0] = fmaf(a3, b0, acc[3][0]); acc[3][1] = fmaf(a3, b1, acc[3][1]);
        acc[3][2] = fmaf(a3, b2, acc[3][2]); acc[3][3] = fmaf(a3, b3, acc[3][3]);
    }
    #pragma unroll
    for (int r = 0; r < 4; ++r) {
        int gi = ib + i0 + r;
        uchar4 m;
        m.x = (acc[r][0] != 0.f || gi == jb + j0 + 0) ? 1 : 0;
        m.y = (acc[r][1] != 0.f || gi == jb + j0 + 1) ? 1 : 0;
        m.z = (acc[r][2] != 0.f || gi == jb + j0 + 2) ? 1 : 0;
        m.w = (acc[r][3] != 0.f || gi == jb + j0 + 3) ? 1 : 0;
        *(uchar4*)&mask[gi * NN + jb + j0] = m;
    }
}

// --- Kernel 3: dual GEMM + alE tail --------------------------------------
// xl = A@Wl, xr = A@Wr; alE[r][h] = 0.6*log2(e)*sum_p att[h,p]*xl[r,h,p]
__global__ __launch_bounds__(256) void k_gemm2(const float* __restrict__ A,
                                               const float* __restrict__ Wl,
                                               const float* __restrict__ Wr,
                                               const float* __restrict__ att,
                                               float* __restrict__ xl,
                                               float* __restrict__ xr,
                                               float* __restrict__ alE) {
    __shared__ float wl[64 * 64];
    __shared__ float wr[64 * 64];
    int tid = threadIdx.x;
    for (int t = tid; t < 4096; t += 256) { wl[t] = Wl[t]; wr[t] = Wr[t]; }
    __syncthreads();
    int r = blockIdx.x * 4 + (tid >> 6);
    int c = tid & 63;
    float av = att[c];
    const float* arow = A + r * 64;
    float accl = 0.f, accr = 0.f;
    #pragma unroll
    for (int p = 0; p < 64; ++p) {
        float a = arow[p];
        accl = fmaf(a, wl[p * 64 + c], accl);
        accr = fmaf(a, wr[p * 64 + c], accr);
    }
    xl[r * 64 + c] = accl;
    xr[r * 64 + c] = accr;
    float t = dpp_rowsum16(accl * av);
    if ((c & 15) == 15) alE[(r << 2) | (c >> 4)] = 0.6f * LOG2E * t;
}

// --- Kernel 4: fully fused flash-style GATv2, one block per (b, i-pair) --
// e' = log2e*e = fma(0.4*log2e, sum_p att|xr+xl|, arE + alE_j)
// pe = exp2(e') (no max-subtraction: e bounded); O[p] += pe*xv[p]; l += pe.
// Lane (h,jl) owns 16 contiguous j's: j = wave*256 + jl*16 + s.
template <bool RELU>
__global__ __launch_bounds__(256, 4) void k_attn(
    const float* __restrict__ xl, const float* __restrict__ xr,
    const float* __restrict__ att, const float* __restrict__ alE,
    const float* __restrict__ bias, const unsigned char* __restrict__ mask,
    float* __restrict__ out)
{
    __shared__ float Opart[2][4][NHEAD][PH];  // [ii][wave][h][p]
    __shared__ float Lpart[2][4][NHEAD];

    int tid = threadIdx.x;
    int wave = tid >> 6, lane = tid & 63;
    int h = lane >> 4, jl = lane & 15;
    int b = blockIdx.x >> 9;
    int i0 = (blockIdx.x & 511) << 1;
    int j0 = (wave << 8) + (jl << 4);          // this lane's 16 contiguous j's

    const float* xlb = xlb = xl + (b << 16);
    const float* alp = alE + (b << 12);

    // persistent fragments
    float at[16], xr0[16], xr1[16];
    {
        const float4* ap = (const float4*)(att + (h << 4));
        const float4* r0 = (const float4*)(xr + ((((b << 10) + i0) << 6) + (h << 4)));
        const float4* r1 = (const float4*)((const float*)r0 + 64);
        #pragma unroll
        for (int q = 0; q < 4; ++q) {
            *(float4*)&at[q << 2] = ap[q];
            *(float4*)&xr0[q << 2] = r0[q];
            *(float4*)&xr1[q << 2] = r1[q];
        }
    }
    float ar0 = 0.f, ar1 = 0.f;
    #pragma unroll
    for (int p = 0; p < 16; ++p) {
        ar0 = fmaf(at[p], xr0[p], ar0);
        ar1 = fmaf(at[p], xr1[p], ar1);
    }
    ar0 *= 0.6f * LOG2E;
    ar1 *= 0.6f * LOG2E;

    // pack this lane's 16 mask bytes (values 0/1) into 16 bits, rows i0,i0+1
    unsigned mb0 = 0, mb1 = 0;
    {
        const unsigned* m0p = (const unsigned*)(mask + i0 * NN + j0);
        const unsigned* m1p = (const unsigned*)(mask + (i0 + 1) * NN + j0);
        #pragma unroll
        for (int q = 0; q < 4; ++q) {
            unsigned w0 = m0p[q], w1 = m1p[q];
            mb0 |= ((((w0 >> 0) & 1) | ((w0 >> 7) & 2) | ((w0 >> 14) & 4) | ((w0 >> 21) & 8)) << (q << 2));
            mb1 |= ((((w1 >> 0) & 1) | ((w1 >> 7) & 2) | ((w1 >> 14) & 4) | ((w1 >> 21) & 8)) << (q << 2));
        }
    }

    float O0[16], O1[16];
    #pragma unroll
    for (int p = 0; p < 16; ++p) { O0[p] = 0.f; O1[p] = 0.f; }
    float l0 = 0.f, l1 = 0.f;

    const float* xj = xlb + (j0 << 6) + (h << 4);
    const float* alj = alp + (j0 << 2) + h;

    for (int s = 0; s < 16; ++s) {
        float xv[16];
        const float4* xp = (const float4*)(xj + (s << 6));
        *(float4*)&xv[0]  = xp[0];
        *(float4*)&xv[4]  = xp[1];
        *(float4*)&xv[8]  = xp[2];
        *(float4*)&xv[12] = xp[3];
        float al = alj[s << 2];
        float acc0 = 0.f, acc1 = 0.f;
        #pragma unroll
        for (int p = 0; p < 16; ++p) {
            float v0 = xr0[p] + xv[p];
            float v1 = xr1[p] + xv[p];
            acc0 = fmaf(at[p], __builtin_fabsf(v0), acc0);
            acc1 = fmaf(at[p], __builtin_fabsf(v1), acc1);
        }
        float e0 = fmaf(0.4f * LOG2E, acc0, ar0 + al);
        float e1 = fmaf(0.4f * LOG2E, acc1, ar1 + al);
        float pe0 = __builtin_amdgcn_exp2f(e0);
        float pe1 = __builtin_amdgcn_exp2f(e1);
        pe0 = ((mb0 >> s) & 1) ? pe0 : 0.f;
        pe1 = ((mb1 >> s) & 1) ? pe1 : 0.f;
        l0 += pe0;
        l1 += pe1;
        #pragma unroll
        for (int p = 0; p < 16; ++p) {
            O0[p] = fmaf(pe0, xv[p], O0[p]);
            O1[p] = fmaf(pe1, xv[p], O1[p]);
        }
    }

    // reduce across the 16 jl-lanes of each h-group (valid in jl==15)
    #pragma unroll
    for (int p = 0; p < 16; ++p) {
        O0[p] = dpp_rowsum16(O0[p]);
        O1[p] = dpp_rowsum16(O1[p]);
    }
    l0 = dpp_rowsum16(l0);
    l1 = dpp_rowsum16(l1);

    if (jl == 15) {
        #pragma unroll
        for (int q = 0; q < 4; ++q) {
            *(float4*)&Opart[0][wave][h][q << 2] = *(const float4*)&O0[q << 2];
            *(float4*)&Opart[1][wave][h][q << 2] = *(const float4*)&O1[q << 2];
        }
        Lpart[0][wave][h] = l0;
        Lpart[1][wave][h] = l1;
    }
    __syncthreads();

    if (tid < 128) {
        int ii = tid >> 6, c = tid & 63;
        int hh = c >> 4, pp = c & 15;
        float o = Opart[ii][0][hh][pp] + Opart[ii][1][hh][pp] +
                  Opart[ii][2][hh][pp] + Opart[ii][3][hh][pp];
        float l = Lpart[ii][0][hh] + Lpart[ii][1][hh] +
                  Lpart[ii][2][hh] + Lpart[ii][3][hh];
        float res = o / l + bias[c];
        if (RELU) res = fmaxf(res, 0.f);
        out[((b << 10) + i0 + ii) * D + c] = res;
    }
}

extern "C" void kernel_launch(void* const* d_in, const int* in_sizes, int n_in,
                              void* d_out, int out_size, void* d_ws, size_t ws_size,
                              hipStream_t stream) {
    const float* x    = (const float*)d_in[0];
    const float* emb  = (const float*)d_in[1];
    const float* Wl1  = (const float*)d_in[2];
    const float* Wr1  = (const float*)d_in[3];
    const float* att1 = (const float*)d_in[4];
    const float* b1   = (const float*)d_in[5];
    const float* Wl2  = (const float*)d_in[6];
    const float* Wr2  = (const float*)d_in[7];
    const float* att2 = (const float*)d_in[8];
    const float* b2   = (const float*)d_in[9];
    float* out = (float*)d_out;

    float* ne = (float*)d_ws;                                   // 256KB
    unsigned char* mask = (unsigned char*)(ne + NN * D);        // 1MB
    float* xl = (float*)(mask + NN * NN);                       // 512KB
    float* xr = xl + BB * NN * D;                               // 512KB
    float* hbuf = xr + BB * NN * D;                             // 512KB
    float* alE = hbuf + BB * NN * D;                            // 32KB

    k_normalize<<<NN, 64, 0, stream>>>(emb, ne);
    k_mask<<<256, 256, 0, stream>>>(ne, mask);

    k_gemm2<<<BB * NN / 4, 256, 0, stream>>>(x, Wl1, Wr1, att1, xl, xr, alE);
    k_attn<true><<<BB * NN / 2, 256, 0, stream>>>(xl, xr, att1, alE, b1, mask, hbuf);

    k_gemm2<<<BB * NN / 4, 256, 0, stream>>>(hbuf, Wl2, Wr2, att2, xl, xr, alE);
    k_attn<false><<<BB * NN / 2, 256, 0, stream>>>(xl, xr, att2, alE, b2, mask, out);
}

// Round 5
// 145.219 us; speedup vs baseline: 5.6339x; 1.1532x over previous
//
#include <hip/hip_runtime.h>
#include <math.h>

#define NN 1024
#define BB 2
#define D 64
#define NHEAD 4
#define PH 16
#define LOG2E 1.4426950408889634f

template <int CTRL>
__device__ __forceinline__ float dpp_mov(float x) {
    int xi = __builtin_bit_cast(int, x);
    int r = __builtin_amdgcn_update_dpp(0, xi, CTRL, 0xF, 0xF, true);
    return __builtin_bit_cast(float, r);
}

// 16-lane row sum; valid in lane 15 of each row of 16.
__device__ __forceinline__ float dpp_rowsum16(float t) {
    t += dpp_mov<0x111>(t);
    t += dpp_mov<0x112>(t);
    t += dpp_mov<0x114>(t);
    t += dpp_mov<0x118>(t);
    return t;
}

// sum across a 4-lane quad via quad_perm butterfly; valid in ALL quad lanes.
__device__ __forceinline__ float quad_sum4(float t) {
    t += dpp_mov<0xB1>(t);   // quad_perm [1,0,3,2]
    t += dpp_mov<0x4E>(t);   // quad_perm [2,3,0,1]
    return t;
}

// --- Kernel 1: adjacency mask as tiled GEMM on RAW embedding rows --------
// norms are positive & finite, so (ne_i.ne_j != 0) <=> (emb_i.emb_j != 0).
#define MST 65
__global__ __launch_bounds__(256) void k_mask(const float* __restrict__ emb,
                                              unsigned char* __restrict__ mask) {
    __shared__ float As[64 * MST];
    __shared__ float Bs[64 * MST];
    int tid = threadIdx.x;
    int ib = (blockIdx.x & 15) << 6;
    int jb = (blockIdx.x >> 4) << 6;

    #pragma unroll
    for (int r = 0; r < 4; ++r) {
        int q = tid + (r << 8);
        int row = q >> 4, c4 = (q & 15) << 2;
        float4 a = *(const float4*)&emb[(ib + row) * D + c4];
        float4 b = *(const float4*)&emb[(jb + row) * D + c4];
        As[row * MST + c4 + 0] = a.x; As[row * MST + c4 + 1] = a.y;
        As[row * MST + c4 + 2] = a.z; As[row * MST + c4 + 3] = a.w;
        Bs[row * MST + c4 + 0] = b.x; Bs[row * MST + c4 + 1] = b.y;
        Bs[row * MST + c4 + 2] = b.z; Bs[row * MST + c4 + 3] = b.w;
    }
    __syncthreads();

    int i0 = (tid >> 4) << 2;
    int j0 = (tid & 15) << 2;
    float acc[4][4] = {};
    #pragma unroll 8
    for (int k = 0; k < 64; ++k) {
        float a0 = As[(i0 + 0) * MST + k];
        float a1 = As[(i0 + 1) * MST + k];
        float a2 = As[(i0 + 2) * MST + k];
        float a3 = As[(i0 + 3) * MST + k];
        float b0 = Bs[(j0 + 0) * MST + k];
        float b1 = Bs[(j0 + 1) * MST + k];
        float b2 = Bs[(j0 + 2) * MST + k];
        float b3 = Bs[(j0 + 3) * MST + k];
        acc[0][0] = fmaf(a0, b0, acc[0][0]); acc[0][1] = fmaf(a0, b1, acc[0][1]);
        acc[0][2] = fmaf(a0, b2, acc[0][2]); acc[0][3] = fmaf(a0, b3, acc[0][3]);
        acc[1][0] = fmaf(a1, b0, acc[1][0]); acc[1][1] = fmaf(a1, b1, acc[1][1]);
        acc[1][2] = fmaf(a1, b2, acc[1][2]); acc[1][3] = fmaf(a1, b3, acc[1][3]);
        acc[2][0] = fmaf(a2, b0, acc[2][0]); acc[2][1] = fmaf(a2, b1, acc[2][1]);
        acc[2][2] = fmaf(a2, b2, acc[2][2]); acc[2][3] = fmaf(a2, b3, acc[2][3]);
        acc[3][0] = fmaf(a3, b0, acc[3][0]); acc[3][1] = fmaf(a3, b1, acc[3][1]);
        acc[3][2] = fmaf(a3, b2, acc[3][2]); acc[3][3] = fmaf(a3, b3, acc[3][3]);
    }
    #pragma unroll
    for (int r = 0; r < 4; ++r) {
        int gi = ib + i0 + r;
        uchar4 m;
        m.x = (acc[r][0] != 0.f || gi == jb + j0 + 0) ? 1 : 0;
        m.y = (acc[r][1] != 0.f || gi == jb + j0 + 1) ? 1 : 0;
        m.z = (acc[r][2] != 0.f || gi == jb + j0 + 2) ? 1 : 0;
        m.w = (acc[r][3] != 0.f || gi == jb + j0 + 3) ? 1 : 0;
        *(uchar4*)&mask[gi * NN + jb + j0] = m;
    }
}

// --- Kernel 2: dual GEMM + alE tail --------------------------------------
// xl = A@Wl, xr = A@Wr; alE[r][h] = 0.6*log2(e)*sum_p att[h,p]*xl[r,h,p]
__global__ __launch_bounds__(256) void k_gemm2(const float* __restrict__ A,
                                               const float* __restrict__ Wl,
                                               const float* __restrict__ Wr,
                                               const float* __restrict__ att,
                                               float* __restrict__ xl,
                                               float* __restrict__ xr,
                                               float* __restrict__ alE) {
    __shared__ float wl[64 * 64];
    __shared__ float wr[64 * 64];
    int tid = threadIdx.x;
    for (int t = tid; t < 4096; t += 256) { wl[t] = Wl[t]; wr[t] = Wr[t]; }
    __syncthreads();
    int r = blockIdx.x * 4 + (tid >> 6);
    int c = tid & 63;
    float av = att[c];
    const float* arow = A + r * 64;
    float accl = 0.f, accr = 0.f;
    #pragma unroll
    for (int p = 0; p < 64; ++p) {
        float a = arow[p];
        accl = fmaf(a, wl[p * 64 + c], accl);
        accr = fmaf(a, wr[p * 64 + c], accr);
    }
    xl[r * 64 + c] = accl;
    xr[r * 64 + c] = accr;
    float t = dpp_rowsum16(accl * av);
    if ((c & 15) == 15) alE[(r << 2) | (c >> 4)] = 0.6f * LOG2E * t;
}

// --- Kernel 3: fused flash GATv2, quad-cooperative loads -----------------
// lane = 4*jl + h; quad (jl) shares row j = wave*256 + jl*16 + s.
// Lane owns p-set {q*16 + 4h + r} (4 elems of each head-slice q).
// e'[j,q] = quadsum(sum_r at'[q][r]*|xr+xv|) + arE[i][q] + alE[j][q]
// with at' = 0.4*log2e*att (permuted), arE = 1.5*quadsum(at'.xr).
template <bool RELU>
__global__ __launch_bounds__(256, 4) void k_attn(
    const float* __restrict__ xl, const float* __restrict__ xr,
    const float* __restrict__ att, const float* __restrict__ alE,
    const float* __restrict__ bias, const unsigned char* __restrict__ mask,
    float* __restrict__ out)
{
    __shared__ float Opart[2][4][4][64];   // [ii][wave][jlgrp][p]
    __shared__ float Lpart[2][4][4][NHEAD];

    int tid = threadIdx.x;
    int wave = tid >> 6, lane = tid & 63;
    int h = lane & 3, jl = lane >> 2;
    int b = blockIdx.x >> 9;
    int i0 = (blockIdx.x & 511) << 1;
    int j0 = (wave << 8) + (jl << 4);

    const float* xlb = xl + (b << 16);

    // permuted persistent fragments: slot q*4+r  <->  p = q*16 + 4h + r
    float at[16], xr0f[16], xr1f[16];
    {
        const float* ap = att + (h << 2);
        const float* r0 = xr + (((b << 10) + i0) << 6) + (h << 2);
        const float* r1 = r0 + 64;
        #pragma unroll
        for (int q = 0; q < 4; ++q) {
            *(float4*)&at[q << 2]   = *(const float4*)(ap + (q << 4));
            *(float4*)&xr0f[q << 2] = *(const float4*)(r0 + (q << 4));
            *(float4*)&xr1f[q << 2] = *(const float4*)(r1 + (q << 4));
        }
        #pragma unroll
        for (int p = 0; p < 16; ++p) at[p] *= 0.4f * LOG2E;
    }
    // arE[i][q] for all q, in every lane (init-time quad butterfly)
    float ar0q[4], ar1q[4];
    #pragma unroll
    for (int q = 0; q < 4; ++q) {
        float p0 = 0.f, p1 = 0.f;
        #pragma unroll
        for (int r = 0; r < 4; ++r) {
            p0 = fmaf(at[(q << 2) + r], xr0f[(q << 2) + r], p0);
            p1 = fmaf(at[(q << 2) + r], xr1f[(q << 2) + r], p1);
        }
        ar0q[q] = 1.5f * quad_sum4(p0);
        ar1q[q] = 1.5f * quad_sum4(p1);
    }

    // pack this lane's 16 mask bytes into 16 bits, rows i0 and i0+1
    unsigned mb0 = 0, mb1 = 0;
    {
        const unsigned* m0p = (const unsigned*)(mask + i0 * NN + j0);
        const unsigned* m1p = (const unsigned*)(mask + (i0 + 1) * NN + j0);
        #pragma unroll
        for (int q = 0; q < 4; ++q) {
            unsigned w0 = m0p[q], w1 = m1p[q];
            mb0 |= ((((w0 >> 0) & 1) | ((w0 >> 7) & 2) | ((w0 >> 14) & 4) | ((w0 >> 21) & 8)) << (q << 2));
            mb1 |= ((((w1 >> 0) & 1) | ((w1 >> 7) & 2) | ((w1 >> 14) & 4) | ((w1 >> 21) & 8)) << (q << 2));
        }
    }

    float O0[16], O1[16], l0q[4] = {}, l1q[4] = {};
    #pragma unroll
    for (int p = 0; p < 16; ++p) { O0[p] = 0.f; O1[p] = 0.f; }

    const float* xrow = xlb + (j0 << 6) + (h << 2);
    const float* alp  = alE + (b << 12) + (j0 << 2);

    #pragma unroll 2
    for (int s = 0; s < 16; ++s) {
        const float* rp = xrow + (s << 6);
        float xv[16];
        *(float4*)&xv[0]  = *(const float4*)(rp);
        *(float4*)&xv[4]  = *(const float4*)(rp + 16);
        *(float4*)&xv[8]  = *(const float4*)(rp + 32);
        *(float4*)&xv[12] = *(const float4*)(rp + 48);
        float alr[4];
        *(float4*)alr = *(const float4*)(alp + (s << 2));
        bool m0 = (mb0 >> s) & 1, m1 = (mb1 >> s) & 1;

        #pragma unroll
        for (int q = 0; q < 4; ++q) {
            float p0 = 0.f, p1 = 0.f;
            #pragma unroll
            for (int r = 0; r < 4; ++r) {
                float xvv = xv[(q << 2) + r];
                float a = at[(q << 2) + r];
                p0 = fmaf(a, __builtin_fabsf(xr0f[(q << 2) + r] + xvv), p0);
                p1 = fmaf(a, __builtin_fabsf(xr1f[(q << 2) + r] + xvv), p1);
            }
            float e0 = quad_sum4(p0) + (ar0q[q] + alr[q]);
            float e1 = quad_sum4(p1) + (ar1q[q] + alr[q]);
            float pe0 = m0 ? __builtin_amdgcn_exp2f(e0) : 0.f;
            float pe1 = m1 ? __builtin_amdgcn_exp2f(e1) : 0.f;
            l0q[q] += pe0;
            l1q[q] += pe1;
            #pragma unroll
            for (int r = 0; r < 4; ++r) {
                float xvv = xv[(q << 2) + r];
                O0[(q << 2) + r] = fmaf(pe0, xvv, O0[(q << 2) + r]);
                O1[(q << 2) + r] = fmaf(pe1, xvv, O1[(q << 2) + r]);
            }
        }
    }

    // reduce over the 4 jl's within each 16-lane DPP row (stride-4 lanes)
    #pragma unroll
    for (int p = 0; p < 16; ++p) {
        O0[p] += dpp_mov<0x114>(O0[p]);  O0[p] += dpp_mov<0x118>(O0[p]);
        O1[p] += dpp_mov<0x114>(O1[p]);  O1[p] += dpp_mov<0x118>(O1[p]);
    }
    #pragma unroll
    for (int q = 0; q < 4; ++q) {
        l0q[q] += dpp_mov<0x114>(l0q[q]);  l0q[q] += dpp_mov<0x118>(l0q[q]);
        l1q[q] += dpp_mov<0x114>(l1q[q]);  l1q[q] += dpp_mov<0x118>(l1q[q]);
    }

    if ((lane & 15) >= 12) {             // lanes 12..15 of each DPP row
        int k = lane >> 4;               // jl-group
        #pragma unroll
        for (int q = 0; q < 4; ++q) {
            *(float4*)&Opart[0][wave][k][(q << 4) + (h << 2)] = *(const float4*)&O0[q << 2];
            *(float4*)&Opart[1][wave][k][(q << 4) + (h << 2)] = *(const float4*)&O1[q << 2];
        }
        if (h == 0) {
            #pragma unroll
            for (int q = 0; q < 4; ++q) {
                Lpart[0][wave][k][q] = l0q[q];
                Lpart[1][wave][k][q] = l1q[q];
            }
        }
    }
    __syncthreads();

    if (tid < 128) {
        int ii = tid >> 6, c = tid & 63;
        float o = 0.f, l = 0.f;
        #pragma unroll
        for (int w = 0; w < 4; ++w)
            #pragma unroll
            for (int k = 0; k < 4; ++k) {
                o += Opart[ii][w][k][c];
                l += Lpart[ii][w][k][c >> 4];
            }
        float res = o / l + bias[c];
        if (RELU) res = fmaxf(res, 0.f);
        out[((b << 10) + i0 + ii) * D + c] = res;
    }
}

extern "C" void kernel_launch(void* const* d_in, const int* in_sizes, int n_in,
                              void* d_out, int out_size, void* d_ws, size_t ws_size,
                              hipStream_t stream) {
    const float* x    = (const float*)d_in[0];
    const float* emb  = (const float*)d_in[1];
    const float* Wl1  = (const float*)d_in[2];
    const float* Wr1  = (const float*)d_in[3];
    const float* att1 = (const float*)d_in[4];
    const float* b1   = (const float*)d_in[5];
    const float* Wl2  = (const float*)d_in[6];
    const float* Wr2  = (const float*)d_in[7];
    const float* att2 = (const float*)d_in[8];
    const float* b2   = (const float*)d_in[9];
    float* out = (float*)d_out;

    unsigned char* mask = (unsigned char*)d_ws;                 // 1MB
    float* xl = (float*)(mask + NN * NN);                       // 512KB
    float* xr = xl + BB * NN * D;                               // 512KB
    float* hbuf = xr + BB * NN * D;                             // 512KB
    float* alE = hbuf + BB * NN * D;                            // 32KB

    k_mask<<<256, 256, 0, stream>>>(emb, mask);

    k_gemm2<<<BB * NN / 4, 256, 0, stream>>>(x, Wl1, Wr1, att1, xl, xr, alE);
    k_attn<true><<<BB * NN / 2, 256, 0, stream>>>(xl, xr, att1, alE, b1, mask, hbuf);

    k_gemm2<<<BB * NN / 4, 256, 0, stream>>>(hbuf, Wl2, Wr2, att2, xl, xr, alE);
    k_attn<false><<<BB * NN / 2, 256, 0, stream>>>(xl, xr, att2, alE, b2, mask, out);
}